// Round 12
// baseline (346.896 us; speedup 1.0000x reference)
//
#include <hip/hip_runtime.h>
#include <math.h>

#define D_MODEL 512
#define NHEADS 8
#define DK 64
#define BATCH 2
#define SEQ 4096
#define NIT 32          // 2048 keys per split / 64-key tiles
// log2(e)/8 folded into Q projection: scores in log2 domain, softmax uses exp2.
#define ATTN_SCALE 0.18033688011112043f

typedef _Float16 half8 __attribute__((ext_vector_type(8)));
typedef _Float16 half4 __attribute__((ext_vector_type(4)));
typedef __fp16 pkhalf2 __attribute__((ext_vector_type(2)));
typedef float f32x4 __attribute__((ext_vector_type(4)));
typedef float f32x16 __attribute__((ext_vector_type(16)));

union Pk8 { _Float16 h[8]; uint4 u; };
union Pk4 { _Float16 h[4]; uint2 u; };
union Pkz { pkhalf2 h2[2]; uint2 u; };
union Un4 { uint2 u; _Float16 h[4]; };
union PFu { unsigned int u[4]; half8 h8; };

#if __has_builtin(__builtin_amdgcn_exp2f)
#define EXP2F __builtin_amdgcn_exp2f
#else
#define EXP2F exp2f
#endif

#define MFMA16(a, b, c) __builtin_amdgcn_mfma_f32_16x16x32_f16((a), (b), (c), 0, 0, 0)
#define MFMA32(a, b, c) __builtin_amdgcn_mfma_f32_32x32x16_f16((a), (b), (c), 0, 0, 0)

// in-place cross-half lane exchange: x[32..63] <- y_old[0..31], y[0..31] <- x_old[32..63]
#define PLSWAP(x, y) asm volatile("v_permlane32_swap_b32 %0, %1" : "+v"(x), "+v"(y))

__device__ __forceinline__ unsigned int cvtpk(float a, float b) {
    union { pkhalf2 h; unsigned int u; } u_;
    u_.h = __builtin_amdgcn_cvt_pkrtz(a, b);
    return u_.u;
}

__device__ __forceinline__ void gload_lds16(const _Float16* g, _Float16* l) {
    __builtin_amdgcn_global_load_lds(
        (const __attribute__((address_space(1))) void*)g,
        (__attribute__((address_space(3))) void*)l, 16, 0, 0);
}

// ============================================================================
// QKV projection GEMM, r12: 256x256 tile (r11) + LDS-TRANSPOSED EPILOGUES.
//  - z<2 (Q/K, row-major out): MFMA operands SWAPPED -> fragments hold 4
//    consecutive n at fixed m. Pack uint2 -> LDS [m][n] (XOR-swizzled),
//    barrier, stream out 256 B/thread contiguous = 16 global_store_dwordx4.
//    Replaces 128 scalar global_store_short per thread.
//  - z==2 (V^T out): unswapped -> fragments 4 consecutive s at fixed n ->
//    LDS [n][s], stream out 256 B runs along s. Kills the 8 B @ 8 KB-stride
//    scatter (~8x write amplification).
//  - Staging LDS (128 KB) is reused as the transpose buffer post-loop.
// ============================================================================
__global__ __launch_bounds__(512)
void gemm_qkv(const float* __restrict__ Aq, const float* __restrict__ Ak,
              const float* __restrict__ Av,
              const float* __restrict__ Wq, const float* __restrict__ Wk,
              const float* __restrict__ Wv,
              const float* __restrict__ bq, const float* __restrict__ bk,
              const float* __restrict__ bv,
              _Float16* __restrict__ Qf, _Float16* __restrict__ Kf,
              _Float16* __restrict__ Vtf) {
    const int z = blockIdx.z;
    const float* A    = z == 0 ? Aq : (z == 1 ? Ak : Av);
    const float* W    = z == 0 ? Wq : (z == 1 ? Wk : Wv);
    const float* bias = z == 0 ? bq : (z == 1 ? bk : bv);

    __shared__ __align__(16) _Float16 smem[4 * 256 * 64];   // 128 KB
    #define sAbuf(B) (smem + (B) * 16384)
    #define sWbuf(B) (smem + 32768 + (B) * 16384)

    const int t    = threadIdx.x;
    const int lane = t & 63, wave = t >> 6;     // wave 0..7
    const int col  = lane & 15, quad = lane >> 4;
    const int wm   = (wave & 3) * 64;           // 4 row-groups of 64
    const int wn   = (wave >> 2) * 128;         // 2 col-groups of 128
    const int m0   = blockIdx.y * 256, n0 = blockIdx.x * 256;

    const int subrow = lane >> 3;
    const int schunk = ((lane & 7) ^ subrow) * 8;

    const float* aBase = A + (size_t)(m0 + wave * 32 + subrow) * 512 + schunk;
    const float* wBase = W + (size_t)(n0 + wave * 32 + subrow) * 512 + schunk;

    float4 ar[4][2], wr[4][2];
    #define LOAD_A(K0)                                                            \
        do {                                                                       \
            _Pragma("unroll")                                                      \
            for (int j = 0; j < 4; ++j) {                                          \
                const float* s = aBase + (size_t)(j * 8) * 512 + (K0);             \
                ar[j][0] = *(const float4*)s;                                      \
                ar[j][1] = *(const float4*)(s + 4);                                \
            }                                                                      \
        } while (0)
    #define LOAD_W(K0)                                                            \
        do {                                                                       \
            _Pragma("unroll")                                                      \
            for (int j = 0; j < 4; ++j) {                                          \
                const float* s = wBase + (size_t)(j * 8) * 512 + (K0);             \
                wr[j][0] = *(const float4*)s;                                      \
                wr[j][1] = *(const float4*)(s + 4);                                \
            }                                                                      \
        } while (0)
    #define WRITE_A(BUF)                                                           \
        do {                                                                       \
            _Pragma("unroll")                                                      \
            for (int j = 0; j < 4; ++j) {                                          \
                uint4 p;                                                           \
                p.x = cvtpk(ar[j][0].x, ar[j][0].y);                               \
                p.y = cvtpk(ar[j][0].z, ar[j][0].w);                               \
                p.z = cvtpk(ar[j][1].x, ar[j][1].y);                               \
                p.w = cvtpk(ar[j][1].z, ar[j][1].w);                               \
                *(uint4*)&sAbuf(BUF)[(wave * 32 + j * 8) * 64 + lane * 8] = p;     \
            }                                                                      \
        } while (0)
    #define WRITE_W(BUF)                                                           \
        do {                                                                       \
            _Pragma("unroll")                                                      \
            for (int j = 0; j < 4; ++j) {                                          \
                uint4 q;                                                           \
                q.x = cvtpk(wr[j][0].x, wr[j][0].y);                               \
                q.y = cvtpk(wr[j][0].z, wr[j][0].w);                               \
                q.z = cvtpk(wr[j][1].x, wr[j][1].y);                               \
                q.w = cvtpk(wr[j][1].z, wr[j][1].w);                               \
                *(uint4*)&sWbuf(BUF)[(wave * 32 + j * 8) * 64 + lane * 8] = q;     \
            }                                                                      \
        } while (0)

    f32x4 acc[4][8] = {};

    LOAD_A(0);
    LOAD_W(0);
    WRITE_A(0);
    WRITE_W(0);

    for (int ck = 0; ck < 8; ++ck) {
        const int cur = ck & 1;
        __syncthreads();
        if (ck + 1 < 8) LOAD_A((ck + 1) * 64);

        // ---- kc = 0 ----
        {
            const int pos = (quad ^ (col & 7)) * 8;
            half8 af[4], wf[8];
            #pragma unroll
            for (int mt = 0; mt < 4; ++mt)
                af[mt] = *(const half8*)&sAbuf(cur)[(wm + mt * 16 + col) * 64 + pos];
            #pragma unroll
            for (int nt = 0; nt < 8; ++nt)
                wf[nt] = *(const half8*)&sWbuf(cur)[(wn + nt * 16 + col) * 64 + pos];
            if (z < 2) {
                #pragma unroll
                for (int mt = 0; mt < 4; ++mt)
                    #pragma unroll
                    for (int nt = 0; nt < 8; ++nt)
                        acc[mt][nt] = MFMA16(wf[nt], af[mt], acc[mt][nt]);
            } else {
                #pragma unroll
                for (int mt = 0; mt < 4; ++mt)
                    #pragma unroll
                    for (int nt = 0; nt < 8; ++nt)
                        acc[mt][nt] = MFMA16(af[mt], wf[nt], acc[mt][nt]);
            }
        }

        if (ck + 1 < 8) {
            WRITE_A(cur ^ 1);
            LOAD_W((ck + 1) * 64);
        }

        // ---- kc = 1 ----
        {
            const int pos = ((4 + quad) ^ (col & 7)) * 8;
            half8 af[4], wf[8];
            #pragma unroll
            for (int mt = 0; mt < 4; ++mt)
                af[mt] = *(const half8*)&sAbuf(cur)[(wm + mt * 16 + col) * 64 + pos];
            #pragma unroll
            for (int nt = 0; nt < 8; ++nt)
                wf[nt] = *(const half8*)&sWbuf(cur)[(wn + nt * 16 + col) * 64 + pos];
            if (z < 2) {
                #pragma unroll
                for (int mt = 0; mt < 4; ++mt)
                    #pragma unroll
                    for (int nt = 0; nt < 8; ++nt)
                        acc[mt][nt] = MFMA16(wf[nt], af[mt], acc[mt][nt]);
            } else {
                #pragma unroll
                for (int mt = 0; mt < 4; ++mt)
                    #pragma unroll
                    for (int nt = 0; nt < 8; ++nt)
                        acc[mt][nt] = MFMA16(af[mt], wf[nt], acc[mt][nt]);
            }
        }

        if (ck + 1 < 8) WRITE_W(cur ^ 1);
    }

    __syncthreads();   // staging reads done; smem becomes transpose buffer

    if (z < 2) {
        // ---- swapped fragments: (n = wn+nt*16+quad*4+r, m = wm+mt*16+col) ----
        const float alpha = z == 0 ? ATTN_SCALE : 1.0f;
        #pragma unroll
        for (int nt = 0; nt < 8; ++nt) {
            const float4 b4 = *(const float4*)&bias[n0 + wn + nt * 16 + quad * 4];
            const int nch = (wn + nt * 16 + quad * 4) >> 2;   // logical 4-half chunk
            #pragma unroll
            for (int mt = 0; mt < 4; ++mt) {
                const int ml = wm + mt * 16 + col;
                Pkz v;
                v.h2[0] = __builtin_amdgcn_cvt_pkrtz((acc[mt][nt][0] + b4.x) * alpha,
                                                     (acc[mt][nt][1] + b4.y) * alpha);
                v.h2[1] = __builtin_amdgcn_cvt_pkrtz((acc[mt][nt][2] + b4.z) * alpha,
                                                     (acc[mt][nt][3] + b4.w) * alpha);
                *(uint2*)&smem[ml * 256 + (nch ^ (ml & 63)) * 4] = v.u;
            }
        }
        __syncthreads();
        _Float16* Out = z == 0 ? Qf : Kf;
        const int row = t >> 1, half = t & 1;
        _Float16* dst = Out + (size_t)(m0 + row) * 512 + n0 + half * 128;
        #pragma unroll
        for (int j = 0; j < 16; ++j) {
            const int c0 = half * 32 + j * 2;
            uint2 a = *(const uint2*)&smem[row * 256 + ((c0)     ^ (row & 63)) * 4];
            uint2 b = *(const uint2*)&smem[row * 256 + ((c0 + 1) ^ (row & 63)) * 4];
            uint4 o = make_uint4(a.x, a.y, b.x, b.y);
            *(uint4*)(dst + j * 8) = o;
        }
    } else {
        // ---- unswapped fragments: (m/s = wm+mt*16+quad*4+r, n = wn+nt*16+col) ----
        #pragma unroll
        for (int nt = 0; nt < 8; ++nt) {
            const int nl = wn + nt * 16 + col;
            const float bv = bias[n0 + nl];
            #pragma unroll
            for (int mt = 0; mt < 4; ++mt) {
                const int sch = (wm + mt * 16 + quad * 4) >> 2;
                Pkz v;
                v.h2[0] = __builtin_amdgcn_cvt_pkrtz(acc[mt][nt][0] + bv,
                                                     acc[mt][nt][1] + bv);
                v.h2[1] = __builtin_amdgcn_cvt_pkrtz(acc[mt][nt][2] + bv,
                                                     acc[mt][nt][3] + bv);
                *(uint2*)&smem[nl * 256 + (sch ^ (nl & 63)) * 4] = v.u;
            }
        }
        __syncthreads();
        const int row = t >> 1, half = t & 1;   // row = n_local
        const int n = n0 + row;
        const int hh = n >> 6, d = n & (DK - 1);
        const int b = m0 >> 12, s0 = (m0 & (SEQ - 1)) + half * 128;
        _Float16* dst = Vtf + ((size_t)(b * NHEADS + hh) * DK + d) * SEQ + s0;
        #pragma unroll
        for (int j = 0; j < 16; ++j) {
            const int c0 = half * 32 + j * 2;
            uint2 a = *(const uint2*)&smem[row * 256 + ((c0)     ^ (row & 63)) * 4];
            uint2 b2 = *(const uint2*)&smem[row * 256 + ((c0 + 1) ^ (row & 63)) * 4];
            uint4 o = make_uint4(a.x, a.y, b2.x, b2.y);
            *(uint4*)(dst + j * 8) = o;
        }
    }
    #undef sAbuf
    #undef sWbuf
}

// ============================================================================
// Flash attention (r9 form, unchanged): both K-splits in one 512-thread block,
// in-block flash merge, 64 q/wave, register P via permlane, 32 MFMA32/wave-iter.
// ============================================================================
__global__ __launch_bounds__(512)
void attn_mfma(const _Float16* __restrict__ Qf, const _Float16* __restrict__ Kf,
               const _Float16* __restrict__ Vtf, _Float16* __restrict__ Oh) {
    __shared__ __align__(16) _Float16 sKall[2 * 2 * 64 * 64];  // [sp][cur] 32 KB
    __shared__ __align__(16) _Float16 sVall[2 * 2 * 64 * 64];  // [sp][cur] 32 KB
    __shared__ float2 sMl[256];                                // split-0 (m,l)

    const int t    = threadIdx.x;
    const int lane = t & 63;
    const int wave = t >> 6;          // 0..7
    const int sp   = wave >> 2;       // split
    const int w4   = wave & 3;        // wave within split
    const int l31  = lane & 31;
    const int g    = lane >> 5;

    // grid: x = h + 8*b (XCD = h), y = qblock
    const int h  = blockIdx.x & (NHEADS - 1);
    const int b  = blockIdx.x >> 3;
    const int q0 = blockIdx.y * 256;
    const int kBase = sp * (SEQ / 2);

    const size_t rowBase = (size_t)b * SEQ;
    const size_t vBase   = ((size_t)(b * NHEADS + h)) * DK * SEQ;

    _Float16* sK0 = sKall + sp * 2 * 4096;
    _Float16* sV0 = sVall + sp * 2 * 4096;

    // ---- DMA pointers; issue K/V tile 0 immediately ----
    const int subrow = lane >> 3;
    const int schunk = ((lane & 7) ^ subrow) * 8;
    const _Float16* kP[2];
    const _Float16* vP[2];
    #pragma unroll
    for (int j = 0; j < 2; ++j) {
        const int rw = w4 * 16 + j * 8;
        kP[j] = Kf + (rowBase + kBase + rw + subrow) * 512 + h * 64 + schunk;
        vP[j] = Vtf + vBase + (size_t)(rw + subrow) * SEQ + kBase + schunk;
        gload_lds16(kP[j], sK0 + rw * 64);
        gload_lds16(vP[j], sV0 + rw * 64);
        kP[j] += 64 * 512;
        vP[j] += 64;
    }

    // ---- Q fragments direct from global: qf[qt][kc] ----
    half8 qf[2][4];
    #pragma unroll
    for (int qt = 0; qt < 2; ++qt)
        #pragma unroll
        for (int kc = 0; kc < 4; ++kc)
            qf[qt][kc] = *(const half8*)(Qf +
                (rowBase + q0 + w4 * 64 + qt * 32 + l31) * 512 +
                h * 64 + kc * 16 + g * 8);

    const int rs = l31 & 7;   // row-XOR swizzle key for K/V LDS reads

    float m_r = 0.0f;
    f32x16 nbv = {};          // -m_r broadcast; all-zero in the common path
    float l_r[2] = { 0.0f, 0.0f };
    f32x16 of[2][2] = {};     // [qt][dt]

    for (int itp = 0; itp < NIT; itp += 2) {
        #pragma unroll
        for (int cur = 0; cur < 2; ++cur) {     // compile-time cur
            const int it = itp + cur;
            _Float16* sK = sK0 + cur * 4096;
            _Float16* sV = sV0 + cur * 4096;
            __syncthreads();   // drains DMA(it) + frees buf cur^1
            if (it + 1 < NIT) {
                #pragma unroll
                for (int j = 0; j < 2; ++j) {
                    const int rw = w4 * 16 + j * 8;
                    gload_lds16(kP[j], sK0 + (cur ^ 1) * 4096 + rw * 64);
                    gload_lds16(vP[j], sV0 + (cur ^ 1) * 4096 + rw * 64);
                    kP[j] += 64 * 512;
                    vP[j] += 64;
                }
            }

            #pragma unroll
            for (int kt = 0; kt < 2; ++kt) {
                // ---- S^T = K · Q^T : 8 MFMA, K frag shared across qt ----
                f32x16 sf0, sf1;
                __builtin_amdgcn_s_setprio(1);
                #pragma unroll
                for (int kc = 0; kc < 4; ++kc) {
                    const int pos = ((kc * 2 + g) ^ rs) * 8;
                    half8 kf = *(const half8*)&sK[(kt * 32 + l31) * 64 + pos];
                    sf0 = MFMA32(kf, qf[0][kc], kc == 0 ? nbv : sf0);
                    sf1 = MFMA32(kf, qf[1][kc], kc == 0 ? nbv : sf1);
                }
                __builtin_amdgcn_s_setprio(0);

                // ---- softmax in-register; l accumulated on VALU ----
                float lrs0 = 0.0f, lrs1 = 0.0f;
                #pragma unroll
                for (int j2 = 0; j2 < 16; ++j2) {
                    sf0[j2] = EXP2F(sf0[j2]);  lrs0 += sf0[j2];
                    sf1[j2] = EXP2F(sf1[j2]);  lrs1 += sf1[j2];
                }
                l_r[0] += lrs0;
                l_r[1] += lrs1;

                // ---- P^T -> B frags: 8 cvt_pk + 4 permlane per qt ----
                PFu pf0[2], pf1[2];
                #define MKPF(P, PF)                                                  \
                    do {                                                             \
                        unsigned int x1 = cvtpk(P[0], P[1]),  x2 = cvtpk(P[2], P[3]);\
                        unsigned int y1 = cvtpk(P[4], P[5]),  y2 = cvtpk(P[6], P[7]);\
                        PLSWAP(x1, y1); PLSWAP(x2, y2);                              \
                        PF[0].u[0] = x1; PF[0].u[1] = x2;                            \
                        PF[0].u[2] = y1; PF[0].u[3] = y2;                            \
                        unsigned int a1 = cvtpk(P[8], P[9]),  a2 = cvtpk(P[10], P[11]);\
                        unsigned int b1 = cvtpk(P[12], P[13]), b2 = cvtpk(P[14], P[15]);\
                        PLSWAP(a1, b1); PLSWAP(a2, b2);                              \
                        PF[1].u[0] = a1; PF[1].u[1] = a2;                            \
                        PF[1].u[2] = b1; PF[1].u[3] = b2;                            \
                    } while (0)
                MKPF(sf0, pf0);
                MKPF(sf1, pf1);
                #undef MKPF

                // ---- O^T += V^T·P^T (V frag shared across qt) ----
                __builtin_amdgcn_s_setprio(1);
                #pragma unroll
                for (int ks2 = 0; ks2 < 2; ++ks2) {
                    const int ks = kt * 2 + ks2;
                    const int pos = ((ks * 2 + g) ^ rs) * 8;
                    half8 v0 = *(const half8*)&sV[l31 * 64 + pos];
                    half8 v1 = *(const half8*)&sV[(32 + l31) * 64 + pos];
                    of[0][0] = MFMA32(v0, pf0[ks2].h8, of[0][0]);
                    of[0][1] = MFMA32(v1, pf0[ks2].h8, of[0][1]);
                    of[1][0] = MFMA32(v0, pf1[ks2].h8, of[1][0]);
                    of[1][1] = MFMA32(v1, pf1[ks2].h8, of[1][1]);
                }
                __builtin_amdgcn_s_setprio(0);
            }

            // ---- rare re-center: running l too large -> scale down 2^-10 ----
            if (__any(fmaxf(l_r[0], l_r[1]) > 1048576.0f)) {
                const float al = 0.0009765625f;   // 2^-10
                #pragma unroll
                for (int qt = 0; qt < 2; ++qt) {
                    l_r[qt] *= al;
                    #pragma unroll
                    for (int j2 = 0; j2 < 16; ++j2) {
                        of[qt][0][j2] *= al;
                        of[qt][1][j2] *= al;
                    }
                }
                m_r += 10.0f;
                #pragma unroll
                for (int j2 = 0; j2 < 16; ++j2) nbv[j2] = -m_r;
            }
        }
    }

    // ======== in-block flash combine (split 0 -> LDS, split 1 merges) ========
    __syncthreads();   // all LDS reads of sK/sV done; sKall region reusable
    _Float16* sOex = sKall;   // 256 q x 64 d fp16, XOR-swizzled (32 KB exact)

    if (sp == 0) {
        #pragma unroll
        for (int qt = 0; qt < 2; ++qt) {
            const float l = l_r[qt] + __shfl_xor(l_r[qt], 32);
            const float inv = 1.0f / l;
            const int ql = w4 * 64 + qt * 32 + l31;
            #pragma unroll
            for (int dt = 0; dt < 2; ++dt) {
                #pragma unroll
                for (int m4 = 0; m4 < 4; ++m4) {
                    const int d0 = dt * 32 + 8 * m4 + 4 * g;
                    const int s = (d0 >> 2) ^ ((ql & 7) << 1);
                    Pkz z2;
                    z2.h2[0] = __builtin_amdgcn_cvt_pkrtz(of[qt][dt][4 * m4 + 0] * inv,
                                                          of[qt][dt][4 * m4 + 1] * inv);
                    z2.h2[1] = __builtin_amdgcn_cvt_pkrtz(of[qt][dt][4 * m4 + 2] * inv,
                                                          of[qt][dt][4 * m4 + 3] * inv);
                    *(uint2*)&sOex[ql * 64 + s * 4] = z2.u;
                }
            }
            if (lane < 32) sMl[ql] = make_float2(m_r, l);
        }
    }
    __syncthreads();
    if (sp == 1) {
        #pragma unroll
        for (int qt = 0; qt < 2; ++qt) {
            const float lB = l_r[qt] + __shfl_xor(l_r[qt], 32);
            const int ql = w4 * 64 + qt * 32 + l31;
            const float2 mlA = sMl[ql];
            const float m = fmaxf(mlA.x, m_r);
            float wA = EXP2F(mlA.x - m) * mlA.y;
            float wB = EXP2F(m_r - m) * lB;
            const float inv = 1.0f / (wA + wB);
            wA *= inv;
            const float wBn = wB * inv / lB;   // applied to unnormalized of
            const size_t R = rowBase + q0 + ql;
            #pragma unroll
            for (int dt = 0; dt < 2; ++dt) {
                #pragma unroll
                for (int m4 = 0; m4 < 4; ++m4) {
                    const int d0 = dt * 32 + 8 * m4 + 4 * g;
                    const int s = (d0 >> 2) ^ ((ql & 7) << 1);
                    Un4 oa;
                    oa.u = *(const uint2*)&sOex[ql * 64 + s * 4];
                    Pkz z2;
                    z2.h2[0] = __builtin_amdgcn_cvt_pkrtz(
                        wA * (float)oa.h[0] + wBn * of[qt][dt][4 * m4 + 0],
                        wA * (float)oa.h[1] + wBn * of[qt][dt][4 * m4 + 1]);
                    z2.h2[1] = __builtin_amdgcn_cvt_pkrtz(
                        wA * (float)oa.h[2] + wBn * of[qt][dt][4 * m4 + 2],
                        wA * (float)oa.h[3] + wBn * of[qt][dt][4 * m4 + 3]);
                    *(uint2*)(Oh + R * 512 + h * 64 + d0) = z2.u;
                }
            }
        }
    }
}

// ============================================================================
// Output projection, r12: 128x128 tile + SWAPPED MFMA + LDS-transposed fp32
// epilogue: fragments hold 4 consecutive n at fixed m -> float4 into LDS
// [m][n] (swizzled), barrier, stream 256 B/thread contiguous float4 stores.
// Replaces 64 scalar fp32 stores per thread.
// ============================================================================
__global__ __launch_bounds__(256)
void gemm_out(const _Float16* __restrict__ Ah, const float* __restrict__ W,
              const float* __restrict__ bias, float* __restrict__ C) {
    __shared__ __align__(16) _Float16 smem[4 * 128 * 64];   // 64 KB
    #define sAh(B) (smem + (B) * 8192)
    #define sWh(B) (smem + 16384 + (B) * 8192)

    const int t    = threadIdx.x;
    const int lane = t & 63, wave = t >> 6;
    const int col  = lane & 15, quad = lane >> 4;
    const int wm   = (wave & 1) * 64, wn = (wave >> 1) * 64;
    const int m0   = blockIdx.y * 128, n0 = blockIdx.x * 128;

    const int subrow = lane >> 3;
    const int schunk = ((lane & 7) ^ subrow) * 8;

    const float* wBase = W + (size_t)(n0 + wave * 32 + subrow) * 512 + schunk;

    float4 wr[4][2];
    #define STAGE_A(K0, BUF)                                                       \
        do {                                                                       \
            _Pragma("unroll")                                                      \
            for (int j = 0; j < 4; ++j) {                                          \
                const int rw = wave * 32 + j * 8;                                  \
                gload_lds16(Ah + (size_t)(m0 + rw + subrow) * 512 + (K0) + schunk, \
                            sAh(BUF) + rw * 64);                                   \
            }                                                                      \
        } while (0)
    #define LOAD_WO(K0)                                                           \
        do {                                                                       \
            _Pragma("unroll")                                                      \
            for (int j = 0; j < 4; ++j) {                                          \
                const float* s = wBase + (size_t)(j * 8) * 512 + (K0);             \
                wr[j][0] = *(const float4*)s;                                      \
                wr[j][1] = *(const float4*)(s + 4);                                \
            }                                                                      \
        } while (0)
    #define WRITE_WO(BUF)                                                          \
        do {                                                                       \
            _Pragma("unroll")                                                      \
            for (int j = 0; j < 4; ++j) {                                          \
                uint4 p;                                                           \
                p.x = cvtpk(wr[j][0].x, wr[j][0].y);                               \
                p.y = cvtpk(wr[j][0].z, wr[j][0].w);                               \
                p.z = cvtpk(wr[j][1].x, wr[j][1].y);                               \
                p.w = cvtpk(wr[j][1].z, wr[j][1].w);                               \
                *(uint4*)&sWh(BUF)[(wave * 32 + j * 8) * 64 + lane * 8] = p;       \
            }                                                                      \
        } while (0)

    f32x4 acc[4][4] = {};

    STAGE_A(0, 0);
    LOAD_WO(0);
    WRITE_WO(0);

    for (int ck = 0; ck < 8; ++ck) {
        const int cur = ck & 1;
        __syncthreads();
        if (ck + 1 < 8) {
            STAGE_A((ck + 1) * 64, cur ^ 1);
            LOAD_WO((ck + 1) * 64);
        }

        #pragma unroll
        for (int kc = 0; kc < 2; ++kc) {
            const int pos = ((kc * 4 + quad) ^ (col & 7)) * 8;
            half8 ahf[4], whf[4];
            #pragma unroll
            for (int mt = 0; mt < 4; ++mt)
                ahf[mt] = *(const half8*)&sAh(cur)[(wm + mt * 16 + col) * 64 + pos];
            #pragma unroll
            for (int nt = 0; nt < 4; ++nt)
                whf[nt] = *(const half8*)&sWh(cur)[(wn + nt * 16 + col) * 64 + pos];
            #pragma unroll
            for (int mt = 0; mt < 4; ++mt)
                #pragma unroll
                for (int nt = 0; nt < 4; ++nt)
                    acc[mt][nt] = MFMA16(whf[nt], ahf[mt], acc[mt][nt]);   // SWAPPED
        }

        if (ck + 1 < 8) WRITE_WO(cur ^ 1);
    }

    __syncthreads();   // staging reads done; smem becomes fp32 transpose buffer
    float* tf = (float*)smem;   // 128 x 128 fp32 = 64 KB

    // swapped fragments: (n = wn+nt*16+quad*4+r, m = wm+mt*16+col)
    #pragma unroll
    for (int nt = 0; nt < 4; ++nt) {
        const float4 b4 = *(const float4*)&bias[n0 + wn + nt * 16 + quad * 4];
        const int nch = (wn + nt * 16 + quad * 4) >> 2;   // logical float4 chunk
        #pragma unroll
        for (int mt = 0; mt < 4; ++mt) {
            const int ml = wm + mt * 16 + col;
            float4 v = make_float4(acc[mt][nt][0] + b4.x, acc[mt][nt][1] + b4.y,
                                   acc[mt][nt][2] + b4.z, acc[mt][nt][3] + b4.w);
            *(float4*)&tf[ml * 128 + ((nch ^ (ml & 31)) << 2)] = v;
        }
    }
    __syncthreads();
    const int row = t >> 1, half = t & 1;
    float* dst = C + (size_t)(m0 + row) * 512 + n0 + half * 64;
    #pragma unroll
    for (int j = 0; j < 16; ++j) {
        const int c = half * 16 + j;
        float4 v = *(const float4*)&tf[row * 128 + ((c ^ (row & 31)) << 2)];
        *(float4*)(dst + j * 4) = v;
    }
    #undef sAh
    #undef sWh
}

// ============================================================================
extern "C" void kernel_launch(void* const* d_in, const int* in_sizes, int n_in,
                              void* d_out, int out_size, void* d_ws, size_t ws_size,
                              hipStream_t stream) {
    const float* query = (const float*)d_in[0];
    const float* key   = (const float*)d_in[1];
    const float* value = (const float*)d_in[2];
    const float* w_q   = (const float*)d_in[3];
    const float* b_q   = (const float*)d_in[4];
    const float* w_k   = (const float*)d_in[5];
    const float* b_k   = (const float*)d_in[6];
    const float* w_v   = (const float*)d_in[7];
    const float* b_v   = (const float*)d_in[8];
    const float* w_o   = (const float*)d_in[9];
    const float* b_o   = (const float*)d_in[10];
    float* out = (float*)d_out;

    const size_t plane = (size_t)BATCH * SEQ * D_MODEL;   // 4.19M halves

    _Float16* base = (_Float16*)d_ws;
    _Float16* Oh   = base;                 // attn output (fp16)
    _Float16* Qf   = Oh + plane;
    _Float16* Kf   = Qf + plane;
    _Float16* Vtf  = Kf + plane;

    hipLaunchKernelGGL(gemm_qkv, dim3(D_MODEL / 256, BATCH * SEQ / 256, 3), dim3(512), 0, stream,
                       query, key, value,
                       w_q, w_k, w_v,
                       b_q, b_k, b_v, Qf, Kf, Vtf);

    hipLaunchKernelGGL(attn_mfma, dim3(NHEADS * BATCH, SEQ / 256), dim3(512), 0, stream,
                       Qf, Kf, Vtf, Oh);

    hipLaunchKernelGGL(gemm_out, dim3(D_MODEL / 128, BATCH * SEQ / 128), dim3(256), 0, stream,
                       Oh, w_o, b_o, out);
}